// Round 12
// baseline (188.876 us; speedup 1.0000x reference)
//
#include <hip/hip_runtime.h>
#include <hip/hip_bf16.h>

// PriorScaleShift:
//   x:         (B=1024, S=512) int32 token ids in [0, 32000)
//   mask:      (B, S, 1) float32  (nonnegative)
//   log_scale: (1, 1, V=32000) float32
//   shift:     (1, 1, V) float32
//   out:       (B, 1, V) float32 = exp(log_scale)*presence + shift
// presence[b,v] = 1 iff exists s: x[b,s]==v and mask[b,s] > 0.
//
// Round 12: full-row blocks (1024 x 512 threads = exactly 4 blocks/CU,
// 100% occupancy, one scheduling round).
//   phase 0: each thread loads its (token, mask) early (latency hidden
//            under the copy phase)
//   phase 1: nontemporal-store copy shift -> out row (out stream bypasses
//            L2; shift reads stay normal -> L2-hot, 128 KB)
//   barrier: __syncthreads emits s_waitcnt vmcnt(0) -> copy ordered
//            before fixups
//   phase 2: one token per thread: out[row,v] = expf(ls[v]) + sh[v]
//            (no loop, no chunk filter, no cross-block race; duplicate
//            tokens write identical values -> benign)

#define PSS_VOCAB 32000
#define PSS_SEQ   512
#define PSS_BLOCK 512
#define PSS_VF4   (PSS_VOCAB / 4)   // 8000 float4 per row

typedef float v4f __attribute__((ext_vector_type(4)));

__global__ __launch_bounds__(PSS_BLOCK)
void PriorScaleShift_47467978556092_kernel(const int* __restrict__ x,
                                           const float* __restrict__ mask,
                                           const float* __restrict__ log_scale,
                                           const float* __restrict__ shift,
                                           float* __restrict__ out) {
    const int row = blockIdx.x;
    const int t   = threadIdx.x;

    float* orow = out + (size_t)row * PSS_VOCAB;

    // Phase 0: hoist this thread's (token, mask) — one coalesced dword each.
    const int   v = x[(size_t)row * PSS_SEQ + t];
    const float m = mask[(size_t)row * PSS_SEQ + t];

    // Phase 1: stream shift into the row with nontemporal 16B stores.
    const v4f* s4 = (const v4f*)shift;
    v4f*       o4 = (v4f*)orow;
    #pragma unroll 4
    for (int i = t; i < PSS_VF4; i += PSS_BLOCK)
        __builtin_nontemporal_store(s4[i], &o4[i]);

    __syncthreads();   // vmcnt(0) drain: copy is globally ordered before fixups

    // Phase 2: sparse fixup — one token per thread.
    if (m > 0.0f)
        orow[v] = expf(log_scale[v]) + shift[v];
}

extern "C" void kernel_launch(void* const* d_in, const int* in_sizes, int n_in,
                              void* d_out, int out_size, void* d_ws, size_t ws_size,
                              hipStream_t stream) {
    const int*   x         = (const int*)d_in[0];
    const float* mask      = (const float*)d_in[1];
    const float* log_scale = (const float*)d_in[2];
    const float* shift     = (const float*)d_in[3];
    float* out = (float*)d_out;

    const int batch = in_sizes[0] / PSS_SEQ;   // 1024

    PriorScaleShift_47467978556092_kernel<<<batch, PSS_BLOCK, 0, stream>>>(
        x, mask, log_scale, shift, out);
}